// Round 2
// baseline (1008.610 us; speedup 1.0000x reference)
//
#include <hip/hip_runtime.h>
#include <hip/hip_bf16.h>

#define B_ 8
#define C_ 512
#define T_ 8
#define H_ 28
#define W_ 28
#define N_ (T_*H_*W_)   // 6272
#define HP_ 14
#define WP_ 14
#define M_ (T_*HP_*WP_) // 1568
#define DI_ 256
#define DO_ 512
#define BN_EPS 1e-5f
#define SCALE_LOG2E 0.090168440055560214f  // (1/sqrt(256)) * log2(e)

typedef __attribute__((ext_vector_type(8))) short short8;
typedef __attribute__((ext_vector_type(4))) float float4v;
typedef __attribute__((ext_vector_type(2))) float float2v;

__device__ inline unsigned short f2bf(float f) {
    union { float f; unsigned int u; } v; v.f = f;
    unsigned int u = v.u;
    return (unsigned short)((u + 0x7FFFu + ((u >> 16) & 1u)) >> 16);
}
__device__ inline float bf2f(unsigned short h) {
    union { unsigned int u; float f; } v; v.u = ((unsigned int)h) << 16;
    return v.f;
}

// ---------- transpose + cast x [C,N] f32 -> xT [N,C] bf16 (per b) ----------
__global__ void xpose_x(const float* __restrict__ x, unsigned short* __restrict__ xT) {
    __shared__ float tile[64][65];
    int b = blockIdx.z;
    int c0 = blockIdx.y * 64, n0 = blockIdx.x * 64;
    const float* src = x + (size_t)b * C_ * N_;
    int tx = threadIdx.x & 63, ty = threadIdx.x >> 6;
#pragma unroll
    for (int i = 0; i < 16; i++) {
        int c = ty + i * 4;
        tile[c][tx] = src[(size_t)(c0 + c) * N_ + n0 + tx];
    }
    __syncthreads();
    unsigned short* d = xT + ((size_t)b * N_ + n0) * C_ + c0;
#pragma unroll
    for (int i = 0; i < 16; i++) {
        int n = ty + i * 4;
        d[(size_t)n * C_ + tx] = f2bf(tile[tx][n]);
    }
}

// ---------- maxpool(1,2,2) + transpose: x [C,T,28,28] -> mpT [M, C] bf16 ----------
__global__ void pool_xpose(const float* __restrict__ x, unsigned short* __restrict__ mpT) {
    __shared__ unsigned short tile[196][72];
    int b = blockIdx.z, t = blockIdx.y, c0 = blockIdx.x * 64;
    const float* src = x + (((size_t)b * C_ + c0) * T_ + t) * 784;
    for (int idx = threadIdx.x; idx < 64 * 196; idx += 256) {
        int cc = idx / 196, p = idx - cc * 196;
        int hp = p / 14, wp = p - hp * 14;
        const float* r0 = src + (size_t)cc * T_ * 784 + (2 * hp) * 28 + 2 * wp;
        float2v a = *(const float2v*)r0;
        float2v c = *(const float2v*)(r0 + 28);
        float m = fmaxf(fmaxf(a.x, a.y), fmaxf(c.x, c.y));
        tile[p][cc] = f2bf(m);
    }
    __syncthreads();
    unsigned short* d = mpT + ((size_t)b * M_ + t * 196) * C_ + c0;
    for (int idx = threadIdx.x; idx < 196 * 64; idx += 256) {
        int p = idx >> 6, cc = idx & 63;
        d[(size_t)p * C_ + cc] = tile[p][cc];
    }
}

// ---------- cast f32 -> bf16 ----------
__global__ void cast_w(const float* __restrict__ s, unsigned short* __restrict__ d, int n) {
    int i = blockIdx.x * 256 + threadIdx.x;
    if (i < n) d[i] = f2bf(s[i]);
}

// ---------- generic BT GEMM: D[M,N] = A[M,K] * B[N,K]^T (+bias), bf16 in, f32 acc ----------
// BIAS_MODE: 0 none, 1 bias[col], 2 bias[row].  OUT_F32: 1 -> f32 out, 0 -> bf16 out.
template<int BIAS_MODE, int OUT_F32>
__global__ __launch_bounds__(256) void btgemm(
        const unsigned short* __restrict__ A, size_t strideAb,
        const unsigned short* __restrict__ Bm, size_t strideBb,
        void* __restrict__ Dp, size_t strideDb,
        const float* __restrict__ bias, int Mdim, int Ndim, int Kdim) {
    int b = blockIdx.z;
    const unsigned short* Ab = A + (size_t)b * strideAb;
    const unsigned short* Bb = Bm + (size_t)b * strideBb;
    int m0 = blockIdx.x * 64, n0 = blockIdx.y * 64;
    int wave = threadIdx.x >> 6, lane = threadIdx.x & 63;
    int wm = (wave >> 1) * 32, wn = (wave & 1) * 32;
    int lr = lane & 15, lk = lane >> 4;
    float4v acc[2][2] = {};
    for (int k0 = 0; k0 < Kdim; k0 += 32) {
        short8 a[2], bb[2];
#pragma unroll
        for (int i = 0; i < 2; i++) {
            int ar = m0 + wm + i * 16 + lr; if (ar >= Mdim) ar = Mdim - 1;
            a[i] = *(const short8*)(Ab + (size_t)ar * Kdim + k0 + lk * 8);
            int br = n0 + wn + i * 16 + lr; if (br >= Ndim) br = Ndim - 1;
            bb[i] = *(const short8*)(Bb + (size_t)br * Kdim + k0 + lk * 8);
        }
#pragma unroll
        for (int i = 0; i < 2; i++)
#pragma unroll
            for (int j = 0; j < 2; j++)
                acc[i][j] = __builtin_amdgcn_mfma_f32_16x16x32_bf16(a[i], bb[j], acc[i][j], 0, 0, 0);
    }
#pragma unroll
    for (int i = 0; i < 2; i++)
#pragma unroll
        for (int j = 0; j < 2; j++) {
            int col = n0 + wn + j * 16 + lr;
#pragma unroll
            for (int r = 0; r < 4; r++) {
                int row = m0 + wm + i * 16 + lk * 4 + r;
                if (row < Mdim && col < Ndim) {
                    float v = acc[i][j][r];
                    if (BIAS_MODE == 1) v += bias[col];
                    else if (BIAS_MODE == 2) v += bias[row];
                    if (OUT_F32) ((float*)Dp)[(size_t)b * strideDb + (size_t)row * Ndim + col] = v;
                    else ((unsigned short*)Dp)[(size_t)b * strideDb + (size_t)row * Ndim + col] = f2bf(v);
                }
            }
        }
}

// ---------- split-B GEMM: D[M,N] = A[M,K] * (Bh+Bl)[N,K]^T + bias[row], f32 out ----------
__global__ __launch_bounds__(256) void btgemm_split(
        const unsigned short* __restrict__ A,
        const unsigned short* __restrict__ Bh, const unsigned short* __restrict__ Bl,
        size_t strideBb, float* __restrict__ Dp, size_t strideDb,
        const float* __restrict__ bias, int Mdim, int Ndim, int Kdim) {
    int b = blockIdx.z;
    const unsigned short* Bhb = Bh + (size_t)b * strideBb;
    const unsigned short* Blb = Bl + (size_t)b * strideBb;
    int m0 = blockIdx.x * 64, n0 = blockIdx.y * 64;
    int wave = threadIdx.x >> 6, lane = threadIdx.x & 63;
    int wm = (wave >> 1) * 32, wn = (wave & 1) * 32;
    int lr = lane & 15, lk = lane >> 4;
    float4v acc[2][2] = {};
    for (int k0 = 0; k0 < Kdim; k0 += 32) {
        short8 a[2], bh[2], bl[2];
#pragma unroll
        for (int i = 0; i < 2; i++) {
            int ar = m0 + wm + i * 16 + lr;
            a[i] = *(const short8*)(A + (size_t)ar * Kdim + k0 + lk * 8);
            int br = n0 + wn + i * 16 + lr;
            bh[i] = *(const short8*)(Bhb + (size_t)br * Kdim + k0 + lk * 8);
            bl[i] = *(const short8*)(Blb + (size_t)br * Kdim + k0 + lk * 8);
        }
#pragma unroll
        for (int i = 0; i < 2; i++)
#pragma unroll
            for (int j = 0; j < 2; j++) {
                acc[i][j] = __builtin_amdgcn_mfma_f32_16x16x32_bf16(a[i], bh[j], acc[i][j], 0, 0, 0);
                acc[i][j] = __builtin_amdgcn_mfma_f32_16x16x32_bf16(a[i], bl[j], acc[i][j], 0, 0, 0);
            }
    }
#pragma unroll
    for (int i = 0; i < 2; i++)
#pragma unroll
        for (int j = 0; j < 2; j++) {
            int col = n0 + wn + j * 16 + lr;
#pragma unroll
            for (int r = 0; r < 4; r++) {
                int row = m0 + wm + i * 16 + lk * 4 + r;
                Dp[(size_t)b * strideDb + (size_t)row * Ndim + col] = acc[i][j][r] + bias[row];
            }
        }
}

// ---------- fused attention: tt[n][d] = sum_m softmax_m(theta.phi/16)[n,m] * g[d][m] ----------
// outputs tt as bf16 hi/lo pair
__global__ __launch_bounds__(256) void attn_k(
        const unsigned short* __restrict__ thetaT,  // [B][N][DI]
        const unsigned short* __restrict__ phiT,    // [B][M][DI]
        const unsigned short* __restrict__ g,       // [B][DI][M]
        unsigned short* __restrict__ ttH,           // [B][N][DI]
        unsigned short* __restrict__ ttL) {         // [B][N][DI]
    __shared__ __align__(16) unsigned short plds[4][16][32];
    int b = blockIdx.y;
    int wave = threadIdx.x >> 6, lane = threadIdx.x & 63;
    int n0 = blockIdx.x * 64 + wave * 16;
    int lr = lane & 15, lk = lane >> 4;
    const unsigned short* Q = thetaT + ((size_t)b * N_ + n0) * DI_;
    const unsigned short* P = phiT + (size_t)b * M_ * DI_;
    const unsigned short* G = g + (size_t)b * DI_ * M_;
    short8 q[8];
#pragma unroll
    for (int kd = 0; kd < 8; kd++)
        q[kd] = *(const short8*)(Q + (size_t)lr * DI_ + kd * 32 + lk * 8);
    float4v acc[16] = {};
    float rs[4] = {0.f, 0.f, 0.f, 0.f};
    for (int m0 = 0; m0 < M_; m0 += 32) {
        float4v L[2] = {};
#pragma unroll
        for (int kd = 0; kd < 8; kd++) {
#pragma unroll
            for (int mj = 0; mj < 2; mj++) {
                short8 pb = *(const short8*)(P + (size_t)(m0 + mj * 16 + lr) * DI_ + kd * 32 + lk * 8);
                L[mj] = __builtin_amdgcn_mfma_f32_16x16x32_bf16(q[kd], pb, L[mj], 0, 0, 0);
            }
        }
        __syncthreads();
#pragma unroll
        for (int mj = 0; mj < 2; mj++)
#pragma unroll
            for (int r = 0; r < 4; r++) {
                float e = exp2f(L[mj][r] * SCALE_LOG2E);
                rs[r] += e;
                plds[wave][lk * 4 + r][mj * 16 + lr] = f2bf(e);
            }
        __syncthreads();
        short8 pa = *(const short8*)(&plds[wave][lr][lk * 8]);
#pragma unroll
        for (int fd = 0; fd < 16; fd++) {
            short8 gb = *(const short8*)(G + (size_t)(fd * 16 + lr) * M_ + m0 + lk * 8);
            acc[fd] = __builtin_amdgcn_mfma_f32_16x16x32_bf16(pa, gb, acc[fd], 0, 0, 0);
        }
    }
#pragma unroll
    for (int s = 1; s < 16; s <<= 1)
#pragma unroll
        for (int r = 0; r < 4; r++) rs[r] += __shfl_xor(rs[r], s, 64);
    float inv[4];
#pragma unroll
    for (int r = 0; r < 4; r++) inv[r] = 1.0f / rs[r];
    unsigned short* OH = ttH + ((size_t)b * N_ + n0) * DI_;
    unsigned short* OL = ttL + ((size_t)b * N_ + n0) * DI_;
#pragma unroll
    for (int fd = 0; fd < 16; fd++)
#pragma unroll
        for (int r = 0; r < 4; r++) {
            float v = acc[fd][r] * inv[r];
            unsigned short h = f2bf(v);
            unsigned short l = f2bf(v - bf2f(h));
            OH[(size_t)(lk * 4 + r) * DI_ + fd * 16 + lr] = h;
            OL[(size_t)(lk * 4 + r) * DI_ + fd * 16 + lr] = l;
        }
}

// ---------- BN stats: per channel o over (B, N) ----------
__global__ void bn_stats(const float* __restrict__ out, float* __restrict__ stats) {
    int o = blockIdx.x;
    float s = 0.f, s2 = 0.f;
    for (int b = 0; b < B_; b++) {
        const float* p = out + ((size_t)b * DO_ + o) * N_;
        for (int n = threadIdx.x; n < N_; n += 256) {
            float v = p[n]; s += v; s2 += v * v;
        }
    }
#pragma unroll
    for (int m = 1; m < 64; m <<= 1) { s += __shfl_xor(s, m, 64); s2 += __shfl_xor(s2, m, 64); }
    __shared__ float ws1[4], ws2[4];
    int wave = threadIdx.x >> 6;
    if ((threadIdx.x & 63) == 0) { ws1[wave] = s; ws2[wave] = s2; }
    __syncthreads();
    if (threadIdx.x == 0) {
        float S = ws1[0] + ws1[1] + ws1[2] + ws1[3];
        float S2 = ws2[0] + ws2[1] + ws2[2] + ws2[3];
        const float cnt = (float)(B_ * N_);
        float mean = S / cnt;
        float var = S2 / cnt - mean * mean;
        stats[o] = mean;
        stats[DO_ + o] = rsqrtf(var + BN_EPS);
    }
}

// ---------- BN apply + residual ----------
__global__ void bn_apply(float* __restrict__ out, const float* __restrict__ x,
                         const float* __restrict__ stats, const float* __restrict__ gamma,
                         const float* __restrict__ beta) {
    size_t i = (size_t)blockIdx.x * 256 + threadIdx.x;  // float4 index
    float4v v = ((const float4v*)out)[i];
    float4v xv = ((const float4v*)x)[i];
    int o = (int)((i * 4 / N_) % DO_);
    float mean = stats[o], rsig = stats[DO_ + o];
    float ga = gamma[o], be = beta[o];
    float4v r;
#pragma unroll
    for (int j = 0; j < 4; j++) r[j] = (v[j] - mean) * rsig * ga + be + xv[j];
    ((float4v*)out)[i] = r;
}

extern "C" void kernel_launch(void* const* d_in, const int* in_sizes, int n_in,
                              void* d_out, int out_size, void* d_ws, size_t ws_size,
                              hipStream_t stream) {
    const float* x       = (const float*)d_in[0];
    const float* theta_w = (const float*)d_in[1];
    const float* theta_b = (const float*)d_in[2];
    const float* phi_w   = (const float*)d_in[3];
    const float* phi_b   = (const float*)d_in[4];
    const float* g_w     = (const float*)d_in[5];
    const float* g_b     = (const float*)d_in[6];
    const float* out_w   = (const float*)d_in[7];
    const float* out_b   = (const float*)d_in[8];
    const float* bn_g    = (const float*)d_in[9];
    const float* bn_b    = (const float*)d_in[10];
    float* out = (float*)d_out;

    char* ws = (char*)d_ws;
    size_t off = 0;
    auto alloc = [&](size_t bytes) { void* p = ws + off; off += (bytes + 255) & ~(size_t)255; return p; };
    unsigned short* xT     = (unsigned short*)alloc((size_t)B_ * N_ * C_ * 2);
    unsigned short* mpT    = (unsigned short*)alloc((size_t)B_ * M_ * C_ * 2);
    unsigned short* thetaT = (unsigned short*)alloc((size_t)B_ * N_ * DI_ * 2);
    unsigned short* phiT   = (unsigned short*)alloc((size_t)B_ * M_ * DI_ * 2);
    unsigned short* gbuf   = (unsigned short*)alloc((size_t)B_ * DI_ * M_ * 2);
    unsigned short* wq     = (unsigned short*)alloc((size_t)DI_ * C_ * 2);
    unsigned short* wp     = (unsigned short*)alloc((size_t)DI_ * C_ * 2);
    unsigned short* wg     = (unsigned short*)alloc((size_t)DI_ * C_ * 2);
    unsigned short* wo     = (unsigned short*)alloc((size_t)DO_ * DI_ * 2);
    float* stats           = (float*)alloc((size_t)DO_ * 2 * 4);
    // tt hi/lo reuse xT's space: xT is [B][N][C=512] bf16 = exactly 2x [B][N][DI=256] bf16
    unsigned short* ttH    = xT;
    unsigned short* ttL    = xT + (size_t)B_ * N_ * DI_;

    // weight casts
    cast_w<<<(DI_ * C_ + 255) / 256, 256, 0, stream>>>(theta_w, wq, DI_ * C_);
    cast_w<<<(DI_ * C_ + 255) / 256, 256, 0, stream>>>(phi_w, wp, DI_ * C_);
    cast_w<<<(DI_ * C_ + 255) / 256, 256, 0, stream>>>(g_w, wg, DI_ * C_);
    cast_w<<<(DO_ * DI_ + 255) / 256, 256, 0, stream>>>(out_w, wo, DO_ * DI_);

    // x transpose + pool transpose
    xpose_x<<<dim3(N_ / 64, C_ / 64, B_), 256, 0, stream>>>(x, xT);
    pool_xpose<<<dim3(C_ / 64, T_, B_), 256, 0, stream>>>(x, mpT);

    // theta: [N,DI] = xT[N,C] * wq[DI,C]^T   (bias over cols = theta_b[d])
    btgemm<1, 0><<<dim3(N_ / 64, DI_ / 64, B_), 256, 0, stream>>>(
        xT, (size_t)N_ * C_, wq, 0, thetaT, (size_t)N_ * DI_, theta_b, N_, DI_, C_);
    // phi: [M,DI] = mpT[M,C] * wp[DI,C]^T
    btgemm<1, 0><<<dim3((M_ + 63) / 64, DI_ / 64, B_), 256, 0, stream>>>(
        mpT, (size_t)M_ * C_, wp, 0, phiT, (size_t)M_ * DI_, phi_b, M_, DI_, C_);
    // g: [DI,M] = wg[DI,C] * mpT[M,C]^T  (bias over rows = g_b[d])
    btgemm<2, 0><<<dim3(DI_ / 64, (M_ + 63) / 64, B_), 256, 0, stream>>>(
        wg, 0, mpT, (size_t)M_ * C_, gbuf, (size_t)DI_ * M_, g_b, DI_, M_, C_);

    // attention -> tt hi/lo [N,DI]  (NOTE: ttH/ttL alias xT, which is dead after theta GEMM)
    attn_k<<<dim3(N_ / 64, B_), 256, 0, stream>>>(thetaT, phiT, gbuf, ttH, ttL);

    // out: [DO,N] = wo[DO,DI] * (ttH+ttL)[N,DI]^T  (bias rows = out_b), f32 into d_out
    btgemm_split<<<dim3(DO_ / 64, N_ / 64, B_), 256, 0, stream>>>(
        wo, ttH, ttL, (size_t)N_ * DI_, out, (size_t)DO_ * N_, out_b, DO_, N_, DI_);

    // BN
    bn_stats<<<DO_, 256, 0, stream>>>(out, stats);
    bn_apply<<<(size_t)B_ * DO_ * N_ / 4 / 256, 256, 0, stream>>>(out, x, stats, bn_g, bn_b);
}

// Round 3
// 606.940 us; speedup vs baseline: 1.6618x; 1.6618x over previous
//
#include <hip/hip_runtime.h>
#include <hip/hip_bf16.h>

#define B_ 8
#define C_ 512
#define T_ 8
#define H_ 28
#define W_ 28
#define N_ (T_*H_*W_)   // 6272
#define HP_ 14
#define WP_ 14
#define M_ (T_*HP_*WP_) // 1568
#define DI_ 256
#define DO_ 512
#define BN_EPS 1e-5f
#define SCALE_LOG2E 0.090168440055560214f  // (1/sqrt(256)) * log2(e)

typedef __attribute__((ext_vector_type(8))) short short8;
typedef __attribute__((ext_vector_type(4))) float float4v;
typedef __attribute__((ext_vector_type(2))) float float2v;

__device__ inline unsigned short f2bf(float f) {
    union { float f; unsigned int u; } v; v.f = f;
    unsigned int u = v.u;
    return (unsigned short)((u + 0x7FFFu + ((u >> 16) & 1u)) >> 16);
}
__device__ inline float bf2f(unsigned short h) {
    union { unsigned int u; float f; } v; v.u = ((unsigned int)h) << 16;
    return v.f;
}

// ---------- transpose + cast x [C,N] f32 -> xT [N,C] bf16 (per b) ----------
__global__ void xpose_x(const float* __restrict__ x, unsigned short* __restrict__ xT) {
    __shared__ float tile[64][65];
    int b = blockIdx.z;
    int c0 = blockIdx.y * 64, n0 = blockIdx.x * 64;
    const float* src = x + (size_t)b * C_ * N_;
    int tx = threadIdx.x & 63, ty = threadIdx.x >> 6;
#pragma unroll
    for (int i = 0; i < 16; i++) {
        int c = ty + i * 4;
        tile[c][tx] = src[(size_t)(c0 + c) * N_ + n0 + tx];
    }
    __syncthreads();
    unsigned short* d = xT + ((size_t)b * N_ + n0) * C_ + c0;
#pragma unroll
    for (int i = 0; i < 16; i++) {
        int n = ty + i * 4;
        d[(size_t)n * C_ + tx] = f2bf(tile[tx][n]);
    }
}

// ---------- maxpool(1,2,2) + transpose: x [C,T,28,28] -> mpT [M, C] bf16 ----------
__global__ void pool_xpose(const float* __restrict__ x, unsigned short* __restrict__ mpT) {
    __shared__ unsigned short tile[196][72];
    int b = blockIdx.z, t = blockIdx.y, c0 = blockIdx.x * 64;
    const float* src = x + (((size_t)b * C_ + c0) * T_ + t) * 784;
    for (int idx = threadIdx.x; idx < 64 * 196; idx += 256) {
        int cc = idx / 196, p = idx - cc * 196;
        int hp = p / 14, wp = p - hp * 14;
        const float* r0 = src + (size_t)cc * T_ * 784 + (2 * hp) * 28 + 2 * wp;
        float2v a = *(const float2v*)r0;
        float2v c = *(const float2v*)(r0 + 28);
        float m = fmaxf(fmaxf(a.x, a.y), fmaxf(c.x, c.y));
        tile[p][cc] = f2bf(m);
    }
    __syncthreads();
    unsigned short* d = mpT + ((size_t)b * M_ + t * 196) * C_ + c0;
    for (int idx = threadIdx.x; idx < 196 * 64; idx += 256) {
        int p = idx >> 6, cc = idx & 63;
        d[(size_t)p * C_ + cc] = tile[p][cc];
    }
}

// ---------- cast f32 -> bf16 ----------
__global__ void cast_w(const float* __restrict__ s, unsigned short* __restrict__ d, int n) {
    int i = blockIdx.x * 256 + threadIdx.x;
    if (i < n) d[i] = f2bf(s[i]);
}

// ---------- generic BT GEMM: D[M,N] = A[M,K] * B[N,K]^T (+bias), bf16 in, f32 acc ----------
template<int BIAS_MODE, int OUT_F32>
__global__ __launch_bounds__(256) void btgemm(
        const unsigned short* __restrict__ A, size_t strideAb,
        const unsigned short* __restrict__ Bm, size_t strideBb,
        void* __restrict__ Dp, size_t strideDb,
        const float* __restrict__ bias, int Mdim, int Ndim, int Kdim) {
    int b = blockIdx.z;
    const unsigned short* Ab = A + (size_t)b * strideAb;
    const unsigned short* Bb = Bm + (size_t)b * strideBb;
    int m0 = blockIdx.x * 64, n0 = blockIdx.y * 64;
    int wave = threadIdx.x >> 6, lane = threadIdx.x & 63;
    int wm = (wave >> 1) * 32, wn = (wave & 1) * 32;
    int lr = lane & 15, lk = lane >> 4;
    float4v acc[2][2] = {};
    for (int k0 = 0; k0 < Kdim; k0 += 32) {
        short8 a[2], bb[2];
#pragma unroll
        for (int i = 0; i < 2; i++) {
            int ar = m0 + wm + i * 16 + lr; if (ar >= Mdim) ar = Mdim - 1;
            a[i] = *(const short8*)(Ab + (size_t)ar * Kdim + k0 + lk * 8);
            int br = n0 + wn + i * 16 + lr; if (br >= Ndim) br = Ndim - 1;
            bb[i] = *(const short8*)(Bb + (size_t)br * Kdim + k0 + lk * 8);
        }
#pragma unroll
        for (int i = 0; i < 2; i++)
#pragma unroll
            for (int j = 0; j < 2; j++)
                acc[i][j] = __builtin_amdgcn_mfma_f32_16x16x32_bf16(a[i], bb[j], acc[i][j], 0, 0, 0);
    }
#pragma unroll
    for (int i = 0; i < 2; i++)
#pragma unroll
        for (int j = 0; j < 2; j++) {
            int col = n0 + wn + j * 16 + lr;
#pragma unroll
            for (int r = 0; r < 4; r++) {
                int row = m0 + wm + i * 16 + lk * 4 + r;
                if (row < Mdim && col < Ndim) {
                    float v = acc[i][j][r];
                    if (BIAS_MODE == 1) v += bias[col];
                    else if (BIAS_MODE == 2) v += bias[row];
                    if (OUT_F32) ((float*)Dp)[(size_t)b * strideDb + (size_t)row * Ndim + col] = v;
                    else ((unsigned short*)Dp)[(size_t)b * strideDb + (size_t)row * Ndim + col] = f2bf(v);
                }
            }
        }
}

// ---------- split-B GEMM: D[M,N] = A[M,K] * (Bh+Bl)[N,K]^T + bias[row], f32 out ----------
__global__ __launch_bounds__(256) void btgemm_split(
        const unsigned short* __restrict__ A,
        const unsigned short* __restrict__ Bh, const unsigned short* __restrict__ Bl,
        size_t strideBb, float* __restrict__ Dp, size_t strideDb,
        const float* __restrict__ bias, int Mdim, int Ndim, int Kdim) {
    int b = blockIdx.z;
    const unsigned short* Bhb = Bh + (size_t)b * strideBb;
    const unsigned short* Blb = Bl + (size_t)b * strideBb;
    int m0 = blockIdx.x * 64, n0 = blockIdx.y * 64;
    int wave = threadIdx.x >> 6, lane = threadIdx.x & 63;
    int wm = (wave >> 1) * 32, wn = (wave & 1) * 32;
    int lr = lane & 15, lk = lane >> 4;
    float4v acc[2][2] = {};
    for (int k0 = 0; k0 < Kdim; k0 += 32) {
        short8 a[2], bh[2], bl[2];
#pragma unroll
        for (int i = 0; i < 2; i++) {
            int ar = m0 + wm + i * 16 + lr;
            a[i] = *(const short8*)(A + (size_t)ar * Kdim + k0 + lk * 8);
            int br = n0 + wn + i * 16 + lr;
            bh[i] = *(const short8*)(Bhb + (size_t)br * Kdim + k0 + lk * 8);
            bl[i] = *(const short8*)(Blb + (size_t)br * Kdim + k0 + lk * 8);
        }
#pragma unroll
        for (int i = 0; i < 2; i++)
#pragma unroll
            for (int j = 0; j < 2; j++) {
                acc[i][j] = __builtin_amdgcn_mfma_f32_16x16x32_bf16(a[i], bh[j], acc[i][j], 0, 0, 0);
                acc[i][j] = __builtin_amdgcn_mfma_f32_16x16x32_bf16(a[i], bl[j], acc[i][j], 0, 0, 0);
            }
    }
#pragma unroll
    for (int i = 0; i < 2; i++)
#pragma unroll
        for (int j = 0; j < 2; j++) {
            int col = n0 + wn + j * 16 + lr;
#pragma unroll
            for (int r = 0; r < 4; r++) {
                int row = m0 + wm + i * 16 + lk * 4 + r;
                Dp[(size_t)b * strideDb + (size_t)row * Ndim + col] = acc[i][j][r] + bias[row];
            }
        }
}

// ---------- fused attention, LDS-staged + double-buffered ----------
// Block: 256 thr = 4 waves, 32 q-rows/wave = 128 rows/block. KV tile = 32 m.
// phi tile [32][256] bf16 XOR-swizzled (row-stride 512B); g tile [256][32] linear.
__global__ __launch_bounds__(256, 2) void attn_k(
        const unsigned short* __restrict__ thetaT,  // [B][N][DI]
        const unsigned short* __restrict__ phiT,    // [B][M][DI]
        const unsigned short* __restrict__ g,       // [B][DI][M]
        unsigned short* __restrict__ ttH,           // [B][N][DI]
        unsigned short* __restrict__ ttL) {         // [B][N][DI]
    __shared__ __align__(16) unsigned short phi_s[2][32][256];  // 32KB
    __shared__ __align__(16) unsigned short g_s[2][256][32];    // 32KB
    __shared__ __align__(16) unsigned short plds[4][32][32];    // 8KB
    // batch-per-XCD swizzle: 392 blocks = 49 x 8; b = bid & 7 keeps one batch per XCD
    const int bid = blockIdx.x;
    const int b = bid & 7;
    const int nblk = bid >> 3;
    const int wave = threadIdx.x >> 6, lane = threadIdx.x & 63;
    const int lr = lane & 15, lk = lane >> 4;
    const int n0 = nblk * 128 + wave * 32;
    const unsigned short* Q  = thetaT + ((size_t)b * N_ + n0) * DI_;
    const unsigned short* Pg = phiT + (size_t)b * M_ * DI_;
    const unsigned short* G  = g + (size_t)b * DI_ * M_;

    short8 q[2][8];
#pragma unroll
    for (int i = 0; i < 2; i++)
#pragma unroll
        for (int kd = 0; kd < 8; kd++)
            q[i][kd] = *(const short8*)(Q + (size_t)(i * 16 + lr) * DI_ + kd * 32 + lk * 8);

    float4v acc[2][16] = {};
    float rs[2][4] = {};

    auto stage = [&](int bufi, int t) {
        const unsigned short* phiRow = Pg + (size_t)t * 32 * DI_;
#pragma unroll
        for (int j = 0; j < 4; j++) {
            int chunk = wave * 4 + j;
            int row = chunk * 2 + (lane >> 5);
            int qq = ((lane & 31) * 16) ^ ((row & 7) << 4);  // inverse-swizzled source
            const unsigned short* src = phiRow + (size_t)row * DI_ + (qq >> 1);
            unsigned short* dst = &phi_s[bufi][0][0] + chunk * 512;
            __builtin_amdgcn_global_load_lds(
                (const __attribute__((address_space(1))) unsigned int*)src,
                (__attribute__((address_space(3))) unsigned int*)dst, 16, 0, 0);
        }
#pragma unroll
        for (int j = 0; j < 4; j++) {
            int chunk = wave * 4 + j;
            int d = chunk * 16 + (lane >> 2);
            const unsigned short* src = G + (size_t)d * M_ + t * 32 + (lane & 3) * 8;
            unsigned short* dst = &g_s[bufi][0][0] + chunk * 512;
            __builtin_amdgcn_global_load_lds(
                (const __attribute__((address_space(1))) unsigned int*)src,
                (__attribute__((address_space(3))) unsigned int*)dst, 16, 0, 0);
        }
    };

    stage(0, 0);
    const int hq = (lk * 16) ^ ((lr & 7) << 4);  // per-lane phi read offset (swizzled)
    int buf = 0;
    const int NT = M_ / 32;  // 49
    for (int t = 0; t < NT; t++) {
        if (t + 1 < NT) {
            stage(buf ^ 1, t + 1);
            asm volatile("s_waitcnt vmcnt(8)" ::: "memory");  // current tile done, next 8 in flight
        } else {
            asm volatile("s_waitcnt vmcnt(0)" ::: "memory");
        }
        __syncthreads();
        const char* phiB = (const char*)&phi_s[buf][0][0];
        float4v L[2][2] = {};
#pragma unroll
        for (int kd = 0; kd < 8; kd++) {
            short8 pb0 = *(const short8*)(phiB + lr * 512 + ((kd * 64) ^ hq));
            short8 pb1 = *(const short8*)(phiB + (16 + lr) * 512 + ((kd * 64) ^ hq));
            L[0][0] = __builtin_amdgcn_mfma_f32_16x16x32_bf16(q[0][kd], pb0, L[0][0], 0, 0, 0);
            L[0][1] = __builtin_amdgcn_mfma_f32_16x16x32_bf16(q[0][kd], pb1, L[0][1], 0, 0, 0);
            L[1][0] = __builtin_amdgcn_mfma_f32_16x16x32_bf16(q[1][kd], pb0, L[1][0], 0, 0, 0);
            L[1][1] = __builtin_amdgcn_mfma_f32_16x16x32_bf16(q[1][kd], pb1, L[1][1], 0, 0, 0);
        }
#pragma unroll
        for (int i = 0; i < 2; i++)
#pragma unroll
            for (int mj = 0; mj < 2; mj++)
#pragma unroll
                for (int r = 0; r < 4; r++) {
                    float e = exp2f(L[i][mj][r] * SCALE_LOG2E);
                    rs[i][r] += e;
                    plds[wave][i * 16 + lk * 4 + r][mj * 16 + lr] = f2bf(e);
                }
        short8 pa0 = *(const short8*)(&plds[wave][lr][lk * 8]);
        short8 pa1 = *(const short8*)(&plds[wave][16 + lr][lk * 8]);
#pragma unroll
        for (int fd = 0; fd < 16; fd++) {
            short8 gb = *(const short8*)(&g_s[buf][fd * 16 + lr][lk * 8]);
            acc[0][fd] = __builtin_amdgcn_mfma_f32_16x16x32_bf16(pa0, gb, acc[0][fd], 0, 0, 0);
            acc[1][fd] = __builtin_amdgcn_mfma_f32_16x16x32_bf16(pa1, gb, acc[1][fd], 0, 0, 0);
        }
        __syncthreads();
        buf ^= 1;
    }
#pragma unroll
    for (int s = 1; s < 16; s <<= 1)
#pragma unroll
        for (int i = 0; i < 2; i++)
#pragma unroll
            for (int r = 0; r < 4; r++) rs[i][r] += __shfl_xor(rs[i][r], s, 64);
    float inv[2][4];
#pragma unroll
    for (int i = 0; i < 2; i++)
#pragma unroll
        for (int r = 0; r < 4; r++) inv[i][r] = 1.0f / rs[i][r];
    unsigned short* OH = ttH + ((size_t)b * N_ + n0) * DI_;
    unsigned short* OL = ttL + ((size_t)b * N_ + n0) * DI_;
#pragma unroll
    for (int i = 0; i < 2; i++)
#pragma unroll
        for (int fd = 0; fd < 16; fd++)
#pragma unroll
            for (int r = 0; r < 4; r++) {
                float v = acc[i][fd][r] * inv[i][r];
                unsigned short h = f2bf(v);
                unsigned short l = f2bf(v - bf2f(h));
                size_t idx = (size_t)(i * 16 + lk * 4 + r) * DI_ + fd * 16 + lr;
                OH[idx] = h;
                OL[idx] = l;
            }
}

// ---------- BN stats: per channel o over (B, N) ----------
__global__ void bn_stats(const float* __restrict__ out, float* __restrict__ stats) {
    int o = blockIdx.x;
    float s = 0.f, s2 = 0.f;
    for (int b = 0; b < B_; b++) {
        const float* p = out + ((size_t)b * DO_ + o) * N_;
        for (int n = threadIdx.x; n < N_; n += 256) {
            float v = p[n]; s += v; s2 += v * v;
        }
    }
#pragma unroll
    for (int m = 1; m < 64; m <<= 1) { s += __shfl_xor(s, m, 64); s2 += __shfl_xor(s2, m, 64); }
    __shared__ float ws1[4], ws2[4];
    int wave = threadIdx.x >> 6;
    if ((threadIdx.x & 63) == 0) { ws1[wave] = s; ws2[wave] = s2; }
    __syncthreads();
    if (threadIdx.x == 0) {
        float S = ws1[0] + ws1[1] + ws1[2] + ws1[3];
        float S2 = ws2[0] + ws2[1] + ws2[2] + ws2[3];
        const float cnt = (float)(B_ * N_);
        float mean = S / cnt;
        float var = S2 / cnt - mean * mean;
        stats[o] = mean;
        stats[DO_ + o] = rsqrtf(var + BN_EPS);
    }
}

// ---------- BN apply + residual ----------
__global__ void bn_apply(float* __restrict__ out, const float* __restrict__ x,
                         const float* __restrict__ stats, const float* __restrict__ gamma,
                         const float* __restrict__ beta) {
    size_t i = (size_t)blockIdx.x * 256 + threadIdx.x;  // float4 index
    float4v v = ((const float4v*)out)[i];
    float4v xv = ((const float4v*)x)[i];
    int o = (int)((i * 4 / N_) % DO_);
    float mean = stats[o], rsig = stats[DO_ + o];
    float ga = gamma[o], be = beta[o];
    float4v r;
#pragma unroll
    for (int j = 0; j < 4; j++) r[j] = (v[j] - mean) * rsig * ga + be + xv[j];
    ((float4v*)out)[i] = r;
}

extern "C" void kernel_launch(void* const* d_in, const int* in_sizes, int n_in,
                              void* d_out, int out_size, void* d_ws, size_t ws_size,
                              hipStream_t stream) {
    const float* x       = (const float*)d_in[0];
    const float* theta_w = (const float*)d_in[1];
    const float* theta_b = (const float*)d_in[2];
    const float* phi_w   = (const float*)d_in[3];
    const float* phi_b   = (const float*)d_in[4];
    const float* g_w     = (const float*)d_in[5];
    const float* g_b     = (const float*)d_in[6];
    const float* out_w   = (const float*)d_in[7];
    const float* out_b   = (const float*)d_in[8];
    const float* bn_g    = (const float*)d_in[9];
    const float* bn_b    = (const float*)d_in[10];
    float* out = (float*)d_out;

    char* ws = (char*)d_ws;
    size_t off = 0;
    auto alloc = [&](size_t bytes) { void* p = ws + off; off += (bytes + 255) & ~(size_t)255; return p; };
    unsigned short* xT     = (unsigned short*)alloc((size_t)B_ * N_ * C_ * 2);
    unsigned short* mpT    = (unsigned short*)alloc((size_t)B_ * M_ * C_ * 2);
    unsigned short* thetaT = (unsigned short*)alloc((size_t)B_ * N_ * DI_ * 2);
    unsigned short* phiT   = (unsigned short*)alloc((size_t)B_ * M_ * DI_ * 2);
    unsigned short* gbuf   = (unsigned short*)alloc((size_t)B_ * DI_ * M_ * 2);
    unsigned short* wq     = (unsigned short*)alloc((size_t)DI_ * C_ * 2);
    unsigned short* wp     = (unsigned short*)alloc((size_t)DI_ * C_ * 2);
    unsigned short* wg     = (unsigned short*)alloc((size_t)DI_ * C_ * 2);
    unsigned short* wo     = (unsigned short*)alloc((size_t)DO_ * DI_ * 2);
    float* stats           = (float*)alloc((size_t)DO_ * 2 * 4);
    // tt hi/lo reuse xT's space: xT is [B][N][C=512] bf16 = exactly 2x [B][N][DI=256] bf16
    unsigned short* ttH    = xT;
    unsigned short* ttL    = xT + (size_t)B_ * N_ * DI_;

    // weight casts
    cast_w<<<(DI_ * C_ + 255) / 256, 256, 0, stream>>>(theta_w, wq, DI_ * C_);
    cast_w<<<(DI_ * C_ + 255) / 256, 256, 0, stream>>>(phi_w, wp, DI_ * C_);
    cast_w<<<(DI_ * C_ + 255) / 256, 256, 0, stream>>>(g_w, wg, DI_ * C_);
    cast_w<<<(DO_ * DI_ + 255) / 256, 256, 0, stream>>>(out_w, wo, DO_ * DI_);

    // x transpose + pool transpose
    xpose_x<<<dim3(N_ / 64, C_ / 64, B_), 256, 0, stream>>>(x, xT);
    pool_xpose<<<dim3(C_ / 64, T_, B_), 256, 0, stream>>>(x, mpT);

    // theta: [N,DI] = xT[N,C] * wq[DI,C]^T   (bias over cols = theta_b[d])
    btgemm<1, 0><<<dim3(N_ / 64, DI_ / 64, B_), 256, 0, stream>>>(
        xT, (size_t)N_ * C_, wq, 0, thetaT, (size_t)N_ * DI_, theta_b, N_, DI_, C_);
    // phi: [M,DI] = mpT[M,C] * wp[DI,C]^T
    btgemm<1, 0><<<dim3((M_ + 63) / 64, DI_ / 64, B_), 256, 0, stream>>>(
        mpT, (size_t)M_ * C_, wp, 0, phiT, (size_t)M_ * DI_, phi_b, M_, DI_, C_);
    // g: [DI,M] = wg[DI,C] * mpT[M,C]^T  (bias over rows = g_b[d])
    btgemm<2, 0><<<dim3(DI_ / 64, (M_ + 63) / 64, B_), 256, 0, stream>>>(
        wg, 0, mpT, (size_t)M_ * C_, gbuf, (size_t)DI_ * M_, g_b, DI_, M_, C_);

    // attention -> tt hi/lo [N,DI]  (ttH/ttL alias xT, dead after theta GEMM)
    attn_k<<<dim3((N_ / 128) * 8), 256, 0, stream>>>(thetaT, phiT, gbuf, ttH, ttL);

    // out: [DO,N] = wo[DO,DI] * (ttH+ttL)[N,DI]^T  (bias rows = out_b), f32 into d_out
    btgemm_split<<<dim3(DO_ / 64, N_ / 64, B_), 256, 0, stream>>>(
        wo, ttH, ttL, (size_t)N_ * DI_, out, (size_t)DO_ * N_, out_b, DO_, N_, DI_);

    // BN
    bn_stats<<<DO_, 256, 0, stream>>>(out, stats);
    bn_apply<<<(size_t)B_ * DO_ * N_ / 4 / 256, 256, 0, stream>>>(out, x, stats, bn_g, bn_b);
}

// Round 4
// 545.324 us; speedup vs baseline: 1.8496x; 1.1130x over previous
//
#include <hip/hip_runtime.h>
#include <hip/hip_bf16.h>

#define B_ 8
#define C_ 512
#define T_ 8
#define H_ 28
#define W_ 28
#define N_ (T_*H_*W_)   // 6272
#define HP_ 14
#define WP_ 14
#define M_ (T_*HP_*WP_) // 1568
#define DI_ 256
#define DO_ 512
#define BN_EPS 1e-5f
#define SCALE_LOG2E 0.090168440055560214f  // (1/sqrt(256)) * log2(e)
#define PSUM_COLS 1568                      // 98 nblk * 8 batch * 2 col-waves

typedef __attribute__((ext_vector_type(8))) short short8;
typedef __attribute__((ext_vector_type(4))) float float4v;
typedef __attribute__((ext_vector_type(2))) float float2v;

__device__ inline unsigned short f2bf(float f) {
    union { float f; unsigned int u; } v; v.f = f;
    unsigned int u = v.u;
    return (unsigned short)((u + 0x7FFFu + ((u >> 16) & 1u)) >> 16);
}
__device__ inline float bf2f(unsigned short h) {
    union { unsigned int u; float f; } v; v.u = ((unsigned int)h) << 16;
    return v.f;
}

// ---------- transpose + cast x [C,N] f32 -> xT [N,C] bf16 (per b) ----------
__global__ void xpose_x(const float* __restrict__ x, unsigned short* __restrict__ xT) {
    __shared__ float tile[64][65];
    int b = blockIdx.z;
    int c0 = blockIdx.y * 64, n0 = blockIdx.x * 64;
    const float* src = x + (size_t)b * C_ * N_;
    int tx = threadIdx.x & 63, ty = threadIdx.x >> 6;
#pragma unroll
    for (int i = 0; i < 16; i++) {
        int c = ty + i * 4;
        tile[c][tx] = src[(size_t)(c0 + c) * N_ + n0 + tx];
    }
    __syncthreads();
    unsigned short* d = xT + ((size_t)b * N_ + n0) * C_ + c0;
#pragma unroll
    for (int i = 0; i < 16; i++) {
        int n = ty + i * 4;
        d[(size_t)n * C_ + tx] = f2bf(tile[tx][n]);
    }
}

// ---------- maxpool(1,2,2) + transpose: x [C,T,28,28] -> mpT [M, C] bf16 ----------
__global__ void pool_xpose(const float* __restrict__ x, unsigned short* __restrict__ mpT) {
    __shared__ unsigned short tile[196][72];
    int b = blockIdx.z, t = blockIdx.y, c0 = blockIdx.x * 64;
    const float* src = x + (((size_t)b * C_ + c0) * T_ + t) * 784;
    for (int idx = threadIdx.x; idx < 64 * 196; idx += 256) {
        int cc = idx / 196, p = idx - cc * 196;
        int hp = p / 14, wp = p - hp * 14;
        const float* r0 = src + (size_t)cc * T_ * 784 + (2 * hp) * 28 + 2 * wp;
        float2v a = *(const float2v*)r0;
        float2v c = *(const float2v*)(r0 + 28);
        float m = fmaxf(fmaxf(a.x, a.y), fmaxf(c.x, c.y));
        tile[p][cc] = f2bf(m);
    }
    __syncthreads();
    unsigned short* d = mpT + ((size_t)b * M_ + t * 196) * C_ + c0;
    for (int idx = threadIdx.x; idx < 196 * 64; idx += 256) {
        int p = idx >> 6, cc = idx & 63;
        d[(size_t)p * C_ + cc] = tile[p][cc];
    }
}

// ---------- cast f32 -> bf16 ----------
__global__ void cast_w(const float* __restrict__ s, unsigned short* __restrict__ d, int n) {
    int i = blockIdx.x * 256 + threadIdx.x;
    if (i < n) d[i] = f2bf(s[i]);
}

// ---------- generic BT GEMM (phi / g): D[M,N] = A[M,K]*B[N,K]^T (+bias) ----------
template<int BIAS_MODE>
__global__ __launch_bounds__(256) void btgemm(
        const unsigned short* __restrict__ A, size_t strideAb,
        const unsigned short* __restrict__ Bm, size_t strideBb,
        unsigned short* __restrict__ Dp, size_t strideDb,
        const float* __restrict__ bias, int Mdim, int Ndim, int Kdim) {
    int b = blockIdx.z;
    const unsigned short* Ab = A + (size_t)b * strideAb;
    const unsigned short* Bb = Bm + (size_t)b * strideBb;
    int m0 = blockIdx.x * 64, n0 = blockIdx.y * 64;
    int wave = threadIdx.x >> 6, lane = threadIdx.x & 63;
    int wm = (wave >> 1) * 32, wn = (wave & 1) * 32;
    int lr = lane & 15, lk = lane >> 4;
    float4v acc[2][2] = {};
    for (int k0 = 0; k0 < Kdim; k0 += 32) {
        short8 a[2], bb[2];
#pragma unroll
        for (int i = 0; i < 2; i++) {
            int ar = m0 + wm + i * 16 + lr; if (ar >= Mdim) ar = Mdim - 1;
            a[i] = *(const short8*)(Ab + (size_t)ar * Kdim + k0 + lk * 8);
            int br = n0 + wn + i * 16 + lr; if (br >= Ndim) br = Ndim - 1;
            bb[i] = *(const short8*)(Bb + (size_t)br * Kdim + k0 + lk * 8);
        }
#pragma unroll
        for (int i = 0; i < 2; i++)
#pragma unroll
            for (int j = 0; j < 2; j++)
                acc[i][j] = __builtin_amdgcn_mfma_f32_16x16x32_bf16(a[i], bb[j], acc[i][j], 0, 0, 0);
    }
#pragma unroll
    for (int i = 0; i < 2; i++)
#pragma unroll
        for (int j = 0; j < 2; j++) {
            int col = n0 + wn + j * 16 + lr;
#pragma unroll
            for (int r = 0; r < 4; r++) {
                int row = m0 + wm + i * 16 + lk * 4 + r;
                if (row < Mdim && col < Ndim) {
                    float v = acc[i][j][r];
                    if (BIAS_MODE == 1) v += bias[col];
                    else if (BIAS_MODE == 2) v += bias[row];
                    Dp[(size_t)b * strideDb + (size_t)row * Ndim + col] = f2bf(v);
                }
            }
        }
}

// ---------- theta GEMM, XCD-chunked: thetaT[b][N][DI] = xT[b][N,C] * wq[DI,C]^T + bias[di] ----------
__global__ __launch_bounds__(256) void btgemm_theta(
        const unsigned short* __restrict__ xT, const unsigned short* __restrict__ wq,
        unsigned short* __restrict__ thetaT, const float* __restrict__ bias) {
    int bid = blockIdx.x;                      // 3136 = 8 * 392
    int swz = (bid & 7) * 392 + (bid >> 3);    // each XCD -> one batch (392 blocks)
    int b = swz / 392;
    int rem = swz - b * 392;
    int nblk = rem >> 2, diblk = rem & 3;      // diblk fastest: xT tile reused in-XCD
    const unsigned short* Ab = xT + ((size_t)b * N_ + nblk * 64) * C_;
    const unsigned short* Bb = wq + (size_t)diblk * 64 * C_;
    int wave = threadIdx.x >> 6, lane = threadIdx.x & 63;
    int wm = (wave >> 1) * 32, wn = (wave & 1) * 32;
    int lr = lane & 15, lk = lane >> 4;
    float4v acc[2][2] = {};
    for (int k0 = 0; k0 < C_; k0 += 32) {
        short8 a[2], bb[2];
#pragma unroll
        for (int i = 0; i < 2; i++) {
            a[i] = *(const short8*)(Ab + (size_t)(wm + i * 16 + lr) * C_ + k0 + lk * 8);
            bb[i] = *(const short8*)(Bb + (size_t)(wn + i * 16 + lr) * C_ + k0 + lk * 8);
        }
#pragma unroll
        for (int i = 0; i < 2; i++)
#pragma unroll
            for (int j = 0; j < 2; j++)
                acc[i][j] = __builtin_amdgcn_mfma_f32_16x16x32_bf16(a[i], bb[j], acc[i][j], 0, 0, 0);
    }
    unsigned short* D = thetaT + ((size_t)b * N_ + nblk * 64) * DI_ + diblk * 64;
#pragma unroll
    for (int i = 0; i < 2; i++)
#pragma unroll
        for (int j = 0; j < 2; j++) {
            int col = wn + j * 16 + lr;
            float bv = bias[diblk * 64 + col];
#pragma unroll
            for (int r = 0; r < 4; r++) {
                int row = wm + i * 16 + lk * 4 + r;
                D[(size_t)row * DI_ + col] = f2bf(acc[i][j][r] + bv);
            }
        }
}

// ---------- out GEMM, XCD-chunked, + per-block BN partial sums ----------
// D[b][do][n] = wo[do,:] . (ttH+ttL)[b][n,:] + bias[do]; psum[stat][do][pcol]
__global__ __launch_bounds__(256) void btgemm_split_fused(
        const unsigned short* __restrict__ wo,
        const unsigned short* __restrict__ Bh, const unsigned short* __restrict__ Bl,
        float* __restrict__ Dp, const float* __restrict__ bias,
        float* __restrict__ psum) {
    int bid = blockIdx.x;                      // 6272 = 8 * 784
    int swz = (bid & 7) * 784 + (bid >> 3);    // each XCD -> one batch (784 blocks)
    int b = swz / 784;
    int rem = swz - b * 784;
    int nblk = rem >> 3, doblk = rem & 7;      // doblk fastest: tt tile reused in-XCD
    const unsigned short* Bhb = Bh + ((size_t)b * N_ + nblk * 64) * DI_;
    const unsigned short* Blb = Bl + ((size_t)b * N_ + nblk * 64) * DI_;
    const unsigned short* Ab = wo + (size_t)doblk * 64 * DI_;
    int wave = threadIdx.x >> 6, lane = threadIdx.x & 63;
    int wm = (wave >> 1) * 32, wn = (wave & 1) * 32;   // wm: do-rows, wn: n-cols
    int lr = lane & 15, lk = lane >> 4;
    float4v acc[2][2] = {};
    for (int k0 = 0; k0 < DI_; k0 += 32) {
        short8 a[2], bh[2], bl[2];
#pragma unroll
        for (int i = 0; i < 2; i++) {
            a[i] = *(const short8*)(Ab + (size_t)(wm + i * 16 + lr) * DI_ + k0 + lk * 8);
            bh[i] = *(const short8*)(Bhb + (size_t)(wn + i * 16 + lr) * DI_ + k0 + lk * 8);
            bl[i] = *(const short8*)(Blb + (size_t)(wn + i * 16 + lr) * DI_ + k0 + lk * 8);
        }
#pragma unroll
        for (int i = 0; i < 2; i++)
#pragma unroll
            for (int j = 0; j < 2; j++) {
                acc[i][j] = __builtin_amdgcn_mfma_f32_16x16x32_bf16(a[i], bh[j], acc[i][j], 0, 0, 0);
                acc[i][j] = __builtin_amdgcn_mfma_f32_16x16x32_bf16(a[i], bl[j], acc[i][j], 0, 0, 0);
            }
    }
    float* Db = Dp + (size_t)b * DO_ * N_ + (size_t)doblk * 64 * N_ + nblk * 64;
    float s1[2][4], s2[2][4];
#pragma unroll
    for (int i = 0; i < 2; i++)
#pragma unroll
        for (int r = 0; r < 4; r++) {
            int row = wm + i * 16 + lk * 4 + r;
            float bv = bias[doblk * 64 + row];
            float v0 = acc[i][0][r] + bv, v1 = acc[i][1][r] + bv;
            Db[(size_t)row * N_ + wn + lr] = v0;
            Db[(size_t)row * N_ + wn + 16 + lr] = v1;
            s1[i][r] = v0 + v1;
            s2[i][r] = v0 * v0 + v1 * v1;
        }
    // reduce across the 16 lr lanes
#pragma unroll
    for (int m = 1; m < 16; m <<= 1)
#pragma unroll
        for (int i = 0; i < 2; i++)
#pragma unroll
            for (int r = 0; r < 4; r++) {
                s1[i][r] += __shfl_xor(s1[i][r], m, 64);
                s2[i][r] += __shfl_xor(s2[i][r], m, 64);
            }
    if (lr == 0) {
        int pcol = (b * 98 + nblk) * 2 + (wave & 1);
#pragma unroll
        for (int i = 0; i < 2; i++)
#pragma unroll
            for (int r = 0; r < 4; r++) {
                int row = doblk * 64 + wm + i * 16 + lk * 4 + r;
                psum[(size_t)row * PSUM_COLS + pcol] = s1[i][r];
                psum[(size_t)(DO_ + row) * PSUM_COLS + pcol] = s2[i][r];
            }
    }
}

// ---------- fused attention, LDS-staged + double-buffered (unchanged) ----------
__global__ __launch_bounds__(256, 2) void attn_k(
        const unsigned short* __restrict__ thetaT,
        const unsigned short* __restrict__ phiT,
        const unsigned short* __restrict__ g,
        unsigned short* __restrict__ ttH,
        unsigned short* __restrict__ ttL) {
    __shared__ __align__(16) unsigned short phi_s[2][32][256];
    __shared__ __align__(16) unsigned short g_s[2][256][32];
    __shared__ __align__(16) unsigned short plds[4][32][32];
    const int bid = blockIdx.x;
    const int b = bid & 7;
    const int nblk = bid >> 3;
    const int wave = threadIdx.x >> 6, lane = threadIdx.x & 63;
    const int lr = lane & 15, lk = lane >> 4;
    const int n0 = nblk * 128 + wave * 32;
    const unsigned short* Q  = thetaT + ((size_t)b * N_ + n0) * DI_;
    const unsigned short* Pg = phiT + (size_t)b * M_ * DI_;
    const unsigned short* G  = g + (size_t)b * DI_ * M_;

    short8 q[2][8];
#pragma unroll
    for (int i = 0; i < 2; i++)
#pragma unroll
        for (int kd = 0; kd < 8; kd++)
            q[i][kd] = *(const short8*)(Q + (size_t)(i * 16 + lr) * DI_ + kd * 32 + lk * 8);

    float4v acc[2][16] = {};
    float rs[2][4] = {};

    auto stage = [&](int bufi, int t) {
        const unsigned short* phiRow = Pg + (size_t)t * 32 * DI_;
#pragma unroll
        for (int j = 0; j < 4; j++) {
            int chunk = wave * 4 + j;
            int row = chunk * 2 + (lane >> 5);
            int qq = ((lane & 31) * 16) ^ ((row & 7) << 4);
            const unsigned short* src = phiRow + (size_t)row * DI_ + (qq >> 1);
            unsigned short* dst = &phi_s[bufi][0][0] + chunk * 512;
            __builtin_amdgcn_global_load_lds(
                (const __attribute__((address_space(1))) unsigned int*)src,
                (__attribute__((address_space(3))) unsigned int*)dst, 16, 0, 0);
        }
#pragma unroll
        for (int j = 0; j < 4; j++) {
            int chunk = wave * 4 + j;
            int d = chunk * 16 + (lane >> 2);
            const unsigned short* src = G + (size_t)d * M_ + t * 32 + (lane & 3) * 8;
            unsigned short* dst = &g_s[bufi][0][0] + chunk * 512;
            __builtin_amdgcn_global_load_lds(
                (const __attribute__((address_space(1))) unsigned int*)src,
                (__attribute__((address_space(3))) unsigned int*)dst, 16, 0, 0);
        }
    };

    stage(0, 0);
    const int hq = (lk * 16) ^ ((lr & 7) << 4);
    int buf = 0;
    const int NT = M_ / 32;
    for (int t = 0; t < NT; t++) {
        if (t + 1 < NT) {
            stage(buf ^ 1, t + 1);
            asm volatile("s_waitcnt vmcnt(8)" ::: "memory");
        } else {
            asm volatile("s_waitcnt vmcnt(0)" ::: "memory");
        }
        __syncthreads();
        const char* phiB = (const char*)&phi_s[buf][0][0];
        float4v L[2][2] = {};
#pragma unroll
        for (int kd = 0; kd < 8; kd++) {
            short8 pb0 = *(const short8*)(phiB + lr * 512 + ((kd * 64) ^ hq));
            short8 pb1 = *(const short8*)(phiB + (16 + lr) * 512 + ((kd * 64) ^ hq));
            L[0][0] = __builtin_amdgcn_mfma_f32_16x16x32_bf16(q[0][kd], pb0, L[0][0], 0, 0, 0);
            L[0][1] = __builtin_amdgcn_mfma_f32_16x16x32_bf16(q[0][kd], pb1, L[0][1], 0, 0, 0);
            L[1][0] = __builtin_amdgcn_mfma_f32_16x16x32_bf16(q[1][kd], pb0, L[1][0], 0, 0, 0);
            L[1][1] = __builtin_amdgcn_mfma_f32_16x16x32_bf16(q[1][kd], pb1, L[1][1], 0, 0, 0);
        }
#pragma unroll
        for (int i = 0; i < 2; i++)
#pragma unroll
            for (int mj = 0; mj < 2; mj++)
#pragma unroll
                for (int r = 0; r < 4; r++) {
                    float e = exp2f(L[i][mj][r] * SCALE_LOG2E);
                    rs[i][r] += e;
                    plds[wave][i * 16 + lk * 4 + r][mj * 16 + lr] = f2bf(e);
                }
        short8 pa0 = *(const short8*)(&plds[wave][lr][lk * 8]);
        short8 pa1 = *(const short8*)(&plds[wave][16 + lr][lk * 8]);
#pragma unroll
        for (int fd = 0; fd < 16; fd++) {
            short8 gb = *(const short8*)(&g_s[buf][fd * 16 + lr][lk * 8]);
            acc[0][fd] = __builtin_amdgcn_mfma_f32_16x16x32_bf16(pa0, gb, acc[0][fd], 0, 0, 0);
            acc[1][fd] = __builtin_amdgcn_mfma_f32_16x16x32_bf16(pa1, gb, acc[1][fd], 0, 0, 0);
        }
        __syncthreads();
        buf ^= 1;
    }
#pragma unroll
    for (int s = 1; s < 16; s <<= 1)
#pragma unroll
        for (int i = 0; i < 2; i++)
#pragma unroll
            for (int r = 0; r < 4; r++) rs[i][r] += __shfl_xor(rs[i][r], s, 64);
    float inv[2][4];
#pragma unroll
    for (int i = 0; i < 2; i++)
#pragma unroll
        for (int r = 0; r < 4; r++) inv[i][r] = 1.0f / rs[i][r];
    unsigned short* OH = ttH + ((size_t)b * N_ + n0) * DI_;
    unsigned short* OL = ttL + ((size_t)b * N_ + n0) * DI_;
#pragma unroll
    for (int i = 0; i < 2; i++)
#pragma unroll
        for (int fd = 0; fd < 16; fd++)
#pragma unroll
            for (int r = 0; r < 4; r++) {
                float v = acc[i][fd][r] * inv[i][r];
                unsigned short h = f2bf(v);
                unsigned short l = f2bf(v - bf2f(h));
                size_t idx = (size_t)(i * 16 + lk * 4 + r) * DI_ + fd * 16 + lr;
                OH[idx] = h;
                OL[idx] = l;
            }
}

// ---------- BN finalize: reduce psum -> stats (mean, rsqrt(var+eps)) ----------
__global__ void bn_finalize(const float* __restrict__ psum, float* __restrict__ stats) {
    int o = blockIdx.x;  // 512
    float s = 0.f, q = 0.f;
    for (int c = threadIdx.x; c < PSUM_COLS; c += 256) {
        s += psum[(size_t)o * PSUM_COLS + c];
        q += psum[(size_t)(DO_ + o) * PSUM_COLS + c];
    }
#pragma unroll
    for (int m = 1; m < 64; m <<= 1) { s += __shfl_xor(s, m, 64); q += __shfl_xor(q, m, 64); }
    __shared__ float ws1[4], ws2[4];
    int wave = threadIdx.x >> 6;
    if ((threadIdx.x & 63) == 0) { ws1[wave] = s; ws2[wave] = q; }
    __syncthreads();
    if (threadIdx.x == 0) {
        double S = (double)ws1[0] + ws1[1] + ws1[2] + ws1[3];
        double Q = (double)ws2[0] + ws2[1] + ws2[2] + ws2[3];
        const double cnt = (double)(B_ * N_);
        double mean = S / cnt;
        double var = Q / cnt - mean * mean;
        stats[o] = (float)mean;
        stats[DO_ + o] = (float)(1.0 / sqrt(var + (double)BN_EPS));
    }
}

// ---------- BN apply + residual ----------
__global__ void bn_apply(float* __restrict__ out, const float* __restrict__ x,
                         const float* __restrict__ stats, const float* __restrict__ gamma,
                         const float* __restrict__ beta) {
    size_t i = (size_t)blockIdx.x * 256 + threadIdx.x;
    float4v v = ((const float4v*)out)[i];
    float4v xv = ((const float4v*)x)[i];
    int o = (int)((i * 4 / N_) % DO_);
    float mean = stats[o], rsig = stats[DO_ + o];
    float ga = gamma[o], be = beta[o];
    float4v r;
#pragma unroll
    for (int j = 0; j < 4; j++) r[j] = (v[j] - mean) * rsig * ga + be + xv[j];
    ((float4v*)out)[i] = r;
}

extern "C" void kernel_launch(void* const* d_in, const int* in_sizes, int n_in,
                              void* d_out, int out_size, void* d_ws, size_t ws_size,
                              hipStream_t stream) {
    const float* x       = (const float*)d_in[0];
    const float* theta_w = (const float*)d_in[1];
    const float* theta_b = (const float*)d_in[2];
    const float* phi_w   = (const float*)d_in[3];
    const float* phi_b   = (const float*)d_in[4];
    const float* g_w     = (const float*)d_in[5];
    const float* g_b     = (const float*)d_in[6];
    const float* out_w   = (const float*)d_in[7];
    const float* out_b   = (const float*)d_in[8];
    const float* bn_g    = (const float*)d_in[9];
    const float* bn_b    = (const float*)d_in[10];
    float* out = (float*)d_out;

    char* ws = (char*)d_ws;
    size_t off = 0;
    auto alloc = [&](size_t bytes) { void* p = ws + off; off += (bytes + 255) & ~(size_t)255; return p; };
    unsigned short* xT     = (unsigned short*)alloc((size_t)B_ * N_ * C_ * 2);
    unsigned short* mpT    = (unsigned short*)alloc((size_t)B_ * M_ * C_ * 2);
    unsigned short* thetaT = (unsigned short*)alloc((size_t)B_ * N_ * DI_ * 2);
    unsigned short* phiT   = (unsigned short*)alloc((size_t)B_ * M_ * DI_ * 2);
    unsigned short* gbuf   = (unsigned short*)alloc((size_t)B_ * DI_ * M_ * 2);
    unsigned short* wq     = (unsigned short*)alloc((size_t)DI_ * C_ * 2);
    unsigned short* wp     = (unsigned short*)alloc((size_t)DI_ * C_ * 2);
    unsigned short* wg     = (unsigned short*)alloc((size_t)DI_ * C_ * 2);
    unsigned short* wo     = (unsigned short*)alloc((size_t)DO_ * DI_ * 2);
    float* stats           = (float*)alloc((size_t)DO_ * 2 * 4);
    float* psum            = (float*)alloc((size_t)DO_ * 2 * PSUM_COLS * 4);
    unsigned short* ttH    = xT;
    unsigned short* ttL    = xT + (size_t)B_ * N_ * DI_;

    cast_w<<<(DI_ * C_ + 255) / 256, 256, 0, stream>>>(theta_w, wq, DI_ * C_);
    cast_w<<<(DI_ * C_ + 255) / 256, 256, 0, stream>>>(phi_w, wp, DI_ * C_);
    cast_w<<<(DI_ * C_ + 255) / 256, 256, 0, stream>>>(g_w, wg, DI_ * C_);
    cast_w<<<(DO_ * DI_ + 255) / 256, 256, 0, stream>>>(out_w, wo, DO_ * DI_);

    xpose_x<<<dim3(N_ / 64, C_ / 64, B_), 256, 0, stream>>>(x, xT);
    pool_xpose<<<dim3(C_ / 64, T_, B_), 256, 0, stream>>>(x, mpT);

    // theta: XCD-chunked swizzle (one batch per XCD)
    btgemm_theta<<<3136, 256, 0, stream>>>(xT, wq, thetaT, theta_b);
    // phi: [M,DI] = mpT[M,C] * wp[DI,C]^T
    btgemm<1><<<dim3((M_ + 63) / 64, DI_ / 64, B_), 256, 0, stream>>>(
        mpT, (size_t)M_ * C_, wp, 0, phiT, (size_t)M_ * DI_, phi_b, M_, DI_, C_);
    // g: [DI,M] = wg[DI,C] * mpT[M,C]^T
    btgemm<2><<<dim3(DI_ / 64, (M_ + 63) / 64, B_), 256, 0, stream>>>(
        wg, 0, mpT, (size_t)M_ * C_, gbuf, (size_t)DI_ * M_, g_b, DI_, M_, C_);

    // attention -> tt hi/lo (aliases xT)
    attn_k<<<dim3((N_ / 128) * 8), 256, 0, stream>>>(thetaT, phiT, gbuf, ttH, ttL);

    // out GEMM + BN partials (XCD-chunked)
    btgemm_split_fused<<<6272, 256, 0, stream>>>(wo, ttH, ttL, out, out_b, psum);

    // BN
    bn_finalize<<<DO_, 256, 0, stream>>>(psum, stats);
    bn_apply<<<(size_t)B_ * DO_ * N_ / 4 / 256, 256, 0, stream>>>(out, x, stats, bn_g, bn_b);
}

// Round 5
// 383.357 us; speedup vs baseline: 2.6310x; 1.4225x over previous
//
#include <hip/hip_runtime.h>
#include <hip/hip_bf16.h>

#define B_ 8
#define C_ 512
#define T_ 8
#define H_ 28
#define W_ 28
#define N_ (T_*H_*W_)   // 6272
#define HP_ 14
#define WP_ 14
#define M_ (T_*HP_*WP_) // 1568
#define DI_ 256
#define DO_ 512
#define BN_EPS 1e-5f
#define SCALE_LOG2E 0.090168440055560214f  // (1/sqrt(256)) * log2(e)
#define PSUM_COLS 392                       // 8 batch * 49 nchunk

typedef __attribute__((ext_vector_type(8))) short short8;
typedef __attribute__((ext_vector_type(4))) float float4v;
typedef __attribute__((ext_vector_type(2))) float float2v;

__device__ inline unsigned short f2bf(float f) {
    union { float f; unsigned int u; } v; v.f = f;
    unsigned int u = v.u;
    return (unsigned short)((u + 0x7FFFu + ((u >> 16) & 1u)) >> 16);
}
__device__ inline float bf2f(unsigned short h) {
    union { unsigned int u; float f; } v; v.u = ((unsigned int)h) << 16;
    return v.f;
}

// ---------- transpose + cast x [C,N] f32 -> xT [N,C] bf16 (per b) ----------
__global__ void xpose_x(const float* __restrict__ x, unsigned short* __restrict__ xT) {
    __shared__ float tile[64][65];
    int b = blockIdx.z;
    int c0 = blockIdx.y * 64, n0 = blockIdx.x * 64;
    const float* src = x + (size_t)b * C_ * N_;
    int tx = threadIdx.x & 63, ty = threadIdx.x >> 6;
#pragma unroll
    for (int i = 0; i < 16; i++) {
        int c = ty + i * 4;
        tile[c][tx] = src[(size_t)(c0 + c) * N_ + n0 + tx];
    }
    __syncthreads();
    unsigned short* d = xT + ((size_t)b * N_ + n0) * C_ + c0;
#pragma unroll
    for (int i = 0; i < 16; i++) {
        int n = ty + i * 4;
        d[(size_t)n * C_ + tx] = f2bf(tile[tx][n]);
    }
}

// ---------- maxpool(1,2,2) + transpose: x [C,T,28,28] -> mpT [M, C] bf16 ----------
__global__ void pool_xpose(const float* __restrict__ x, unsigned short* __restrict__ mpT) {
    __shared__ unsigned short tile[196][72];
    int b = blockIdx.z, t = blockIdx.y, c0 = blockIdx.x * 64;
    const float* src = x + (((size_t)b * C_ + c0) * T_ + t) * 784;
    for (int idx = threadIdx.x; idx < 64 * 196; idx += 256) {
        int cc = idx / 196, p = idx - cc * 196;
        int hp = p / 14, wp = p - hp * 14;
        const float* r0 = src + (size_t)cc * T_ * 784 + (2 * hp) * 28 + 2 * wp;
        float2v a = *(const float2v*)r0;
        float2v c = *(const float2v*)(r0 + 28);
        float m = fmaxf(fmaxf(a.x, a.y), fmaxf(c.x, c.y));
        tile[p][cc] = f2bf(m);
    }
    __syncthreads();
    unsigned short* d = mpT + ((size_t)b * M_ + t * 196) * C_ + c0;
    for (int idx = threadIdx.x; idx < 196 * 64; idx += 256) {
        int p = idx >> 6, cc = idx & 63;
        d[(size_t)p * C_ + cc] = tile[p][cc];
    }
}

// ---------- cast f32 -> bf16 ----------
__global__ void cast_w(const float* __restrict__ s, unsigned short* __restrict__ d, int n) {
    int i = blockIdx.x * 256 + threadIdx.x;
    if (i < n) d[i] = f2bf(s[i]);
}

// ---------- generic BT GEMM (phi / g): D[M,N] = A[M,K]*B[N,K]^T (+bias) ----------
template<int BIAS_MODE>
__global__ __launch_bounds__(256) void btgemm(
        const unsigned short* __restrict__ A, size_t strideAb,
        const unsigned short* __restrict__ Bm, size_t strideBb,
        unsigned short* __restrict__ Dp, size_t strideDb,
        const float* __restrict__ bias, int Mdim, int Ndim, int Kdim) {
    int b = blockIdx.z;
    const unsigned short* Ab = A + (size_t)b * strideAb;
    const unsigned short* Bb = Bm + (size_t)b * strideBb;
    int m0 = blockIdx.x * 64, n0 = blockIdx.y * 64;
    int wave = threadIdx.x >> 6, lane = threadIdx.x & 63;
    int wm = (wave >> 1) * 32, wn = (wave & 1) * 32;
    int lr = lane & 15, lk = lane >> 4;
    float4v acc[2][2] = {};
    for (int k0 = 0; k0 < Kdim; k0 += 32) {
        short8 a[2], bb[2];
#pragma unroll
        for (int i = 0; i < 2; i++) {
            int ar = m0 + wm + i * 16 + lr; if (ar >= Mdim) ar = Mdim - 1;
            a[i] = *(const short8*)(Ab + (size_t)ar * Kdim + k0 + lk * 8);
            int br = n0 + wn + i * 16 + lr; if (br >= Ndim) br = Ndim - 1;
            bb[i] = *(const short8*)(Bb + (size_t)br * Kdim + k0 + lk * 8);
        }
#pragma unroll
        for (int i = 0; i < 2; i++)
#pragma unroll
            for (int j = 0; j < 2; j++)
                acc[i][j] = __builtin_amdgcn_mfma_f32_16x16x32_bf16(a[i], bb[j], acc[i][j], 0, 0, 0);
    }
#pragma unroll
    for (int i = 0; i < 2; i++)
#pragma unroll
        for (int j = 0; j < 2; j++) {
            int col = n0 + wn + j * 16 + lr;
#pragma unroll
            for (int r = 0; r < 4; r++) {
                int row = m0 + wm + i * 16 + lk * 4 + r;
                if (row < Mdim && col < Ndim) {
                    float v = acc[i][j][r];
                    if (BIAS_MODE == 1) v += bias[col];
                    else if (BIAS_MODE == 2) v += bias[row];
                    Dp[(size_t)b * strideDb + (size_t)row * Ndim + col] = f2bf(v);
                }
            }
        }
}

// ---------- theta GEMM, LDS-staged: thetaT[b][n][di] = xT[b][n,C] . wq[di,C]^T + bias[di] ----------
// 392 blocks = 8 XCD chunks x 49 nblk. Wave hoists 32 n-rows (a[2][16], 128 VGPR);
// wq staged [32 di][512 k] double-buffered (64KB), XOR-swizzled; 8 di-steps.
__global__ __launch_bounds__(256, 2) void theta_gemm(
        const unsigned short* __restrict__ xT, const unsigned short* __restrict__ wq,
        unsigned short* __restrict__ thetaT, const float* __restrict__ bias) {
    __shared__ __align__(16) unsigned short wqs[2][32][512];  // 64KB
    const int bid = blockIdx.x;
    const int b = bid & 7;
    const int nblk = bid >> 3;  // 0..48
    const int wave = threadIdx.x >> 6, lane = threadIdx.x & 63;
    const int lr = lane & 15, lk = lane >> 4;
    const unsigned short* Ab = xT + ((size_t)b * N_ + nblk * 128 + wave * 32) * C_;

    short8 a[2][16];
#pragma unroll
    for (int i = 0; i < 2; i++)
#pragma unroll
        for (int kd = 0; kd < 16; kd++)
            a[i][kd] = *(const short8*)(Ab + (size_t)(i * 16 + lr) * C_ + kd * 32 + lk * 8);

    auto stage = [&](int bufi, int t) {
#pragma unroll
        for (int j = 0; j < 8; j++) {
            int row = wave * 8 + j;  // 0..31, one 1KB row per chunk
            int qq = (lane * 16) ^ ((row & 7) << 4);  // inverse-swizzled source (bytes)
            const unsigned short* src = wq + (size_t)(t * 32 + row) * C_ + (qq >> 1);
            unsigned short* dst = &wqs[bufi][0][0] + row * 512;
            __builtin_amdgcn_global_load_lds(
                (const __attribute__((address_space(1))) unsigned int*)src,
                (__attribute__((address_space(3))) unsigned int*)dst, 16, 0, 0);
        }
    };

    stage(0, 0);
    const int hq = (lk * 16) ^ ((lr & 7) << 4);
    unsigned short* D = thetaT + ((size_t)b * N_ + nblk * 128 + wave * 32) * DI_;
    int buf = 0;
#pragma unroll
    for (int t = 0; t < 8; t++) {
        if (t < 7) {
            stage(buf ^ 1, t + 1);
            asm volatile("s_waitcnt vmcnt(8)" ::: "memory");
        } else {
            asm volatile("s_waitcnt vmcnt(0)" ::: "memory");
        }
        __syncthreads();
        const char* W = (const char*)&wqs[buf][0][0];
        float4v acc[2][2] = {};
#pragma unroll
        for (int kd = 0; kd < 16; kd++) {
            short8 b0 = *(const short8*)(W + lr * 1024 + ((kd * 64) ^ hq));
            short8 b1 = *(const short8*)(W + (16 + lr) * 1024 + ((kd * 64) ^ hq));
            acc[0][0] = __builtin_amdgcn_mfma_f32_16x16x32_bf16(a[0][kd], b0, acc[0][0], 0, 0, 0);
            acc[0][1] = __builtin_amdgcn_mfma_f32_16x16x32_bf16(a[0][kd], b1, acc[0][1], 0, 0, 0);
            acc[1][0] = __builtin_amdgcn_mfma_f32_16x16x32_bf16(a[1][kd], b0, acc[1][0], 0, 0, 0);
            acc[1][1] = __builtin_amdgcn_mfma_f32_16x16x32_bf16(a[1][kd], b1, acc[1][1], 0, 0, 0);
        }
#pragma unroll
        for (int i = 0; i < 2; i++)
#pragma unroll
            for (int j = 0; j < 2; j++) {
                int col = t * 32 + j * 16 + lr;
                float bv = bias[col];
#pragma unroll
                for (int r = 0; r < 4; r++) {
                    int row = i * 16 + lk * 4 + r;
                    D[(size_t)row * DI_ + col] = f2bf(acc[i][j][r] + bv);
                }
            }
        __syncthreads();
        buf ^= 1;
    }
}

// ---------- out GEMM, LDS-staged, + fused BN partial sums ----------
// 1568 blocks = 8 XCD chunks x (49 nchunk x 4 doblk, doblk fastest).
// Wave hoists 32 wo-rows (a[2][8]); ttH/ttL staged [32 n][256 k] dbuf (64KB); 4 n-steps.
__global__ __launch_bounds__(256, 2) void out_gemm(
        const unsigned short* __restrict__ wo,
        const unsigned short* __restrict__ Bh, const unsigned short* __restrict__ Bl,
        float* __restrict__ Dp, const float* __restrict__ bias,
        float* __restrict__ psum) {
    __shared__ __align__(16) unsigned short tts[2][2][32][256];  // [dbuf][h/l], 64KB
    const int bid = blockIdx.x;
    const int b = bid & 7;
    const int rem = bid >> 3;     // 0..195
    const int doblk = rem & 3;    // 4 (fastest: share staged tt via L2)
    const int nchunk = rem >> 2;  // 0..48
    const int wave = threadIdx.x >> 6, lane = threadIdx.x & 63;
    const int lr = lane & 15, lk = lane >> 4;
    const unsigned short* Ab = wo + (size_t)(doblk * 128 + wave * 32) * DI_;
    const unsigned short* BhB = Bh + ((size_t)b * N_ + nchunk * 128) * DI_;
    const unsigned short* BlB = Bl + ((size_t)b * N_ + nchunk * 128) * DI_;

    short8 a[2][8];
#pragma unroll
    for (int i = 0; i < 2; i++)
#pragma unroll
        for (int kd = 0; kd < 8; kd++)
            a[i][kd] = *(const short8*)(Ab + (size_t)(i * 16 + lr) * DI_ + kd * 32 + lk * 8);

    auto stage = [&](int bufi, int t) {
#pragma unroll
        for (int p = 0; p < 2; p++) {
            const unsigned short* S = p ? BlB : BhB;
#pragma unroll
            for (int j = 0; j < 4; j++) {
                int chunk = wave * 4 + j;
                int row = chunk * 2 + (lane >> 5);
                int qq = (((lane & 31) * 16)) ^ ((row & 7) << 4);
                const unsigned short* src = S + (size_t)(t * 32 + row) * DI_ + (qq >> 1);
                unsigned short* dst = &tts[bufi][p][0][0] + chunk * 512;
                __builtin_amdgcn_global_load_lds(
                    (const __attribute__((address_space(1))) unsigned int*)src,
                    (__attribute__((address_space(3))) unsigned int*)dst, 16, 0, 0);
            }
        }
    };

    stage(0, 0);
    const int hq = (lk * 16) ^ ((lr & 7) << 4);
    float4v acc[4][2][2] = {};
    int buf = 0;
#pragma unroll
    for (int t = 0; t < 4; t++) {
        if (t < 3) {
            stage(buf ^ 1, t + 1);
            asm volatile("s_waitcnt vmcnt(8)" ::: "memory");
        } else {
            asm volatile("s_waitcnt vmcnt(0)" ::: "memory");
        }
        __syncthreads();
        const char* th = (const char*)&tts[buf][0][0][0];
        const char* tl = (const char*)&tts[buf][1][0][0];
#pragma unroll
        for (int kd = 0; kd < 8; kd++) {
            short8 bh0 = *(const short8*)(th + lr * 512 + ((kd * 64) ^ hq));
            short8 bh1 = *(const short8*)(th + (16 + lr) * 512 + ((kd * 64) ^ hq));
            short8 bl0 = *(const short8*)(tl + lr * 512 + ((kd * 64) ^ hq));
            short8 bl1 = *(const short8*)(tl + (16 + lr) * 512 + ((kd * 64) ^ hq));
            acc[t][0][0] = __builtin_amdgcn_mfma_f32_16x16x32_bf16(a[0][kd], bh0, acc[t][0][0], 0, 0, 0);
            acc[t][0][0] = __builtin_amdgcn_mfma_f32_16x16x32_bf16(a[0][kd], bl0, acc[t][0][0], 0, 0, 0);
            acc[t][0][1] = __builtin_amdgcn_mfma_f32_16x16x32_bf16(a[0][kd], bh1, acc[t][0][1], 0, 0, 0);
            acc[t][0][1] = __builtin_amdgcn_mfma_f32_16x16x32_bf16(a[0][kd], bl1, acc[t][0][1], 0, 0, 0);
            acc[t][1][0] = __builtin_amdgcn_mfma_f32_16x16x32_bf16(a[1][kd], bh0, acc[t][1][0], 0, 0, 0);
            acc[t][1][0] = __builtin_amdgcn_mfma_f32_16x16x32_bf16(a[1][kd], bl0, acc[t][1][0], 0, 0, 0);
            acc[t][1][1] = __builtin_amdgcn_mfma_f32_16x16x32_bf16(a[1][kd], bh1, acc[t][1][1], 0, 0, 0);
            acc[t][1][1] = __builtin_amdgcn_mfma_f32_16x16x32_bf16(a[1][kd], bl1, acc[t][1][1], 0, 0, 0);
        }
        __syncthreads();
        buf ^= 1;
    }
    // epilogue: bias, stores, BN partials
    float* Db = Dp + (size_t)b * DO_ * N_;
    float s1[2][4] = {}, s2[2][4] = {};
#pragma unroll
    for (int t = 0; t < 4; t++)
#pragma unroll
        for (int i = 0; i < 2; i++)
#pragma unroll
            for (int r = 0; r < 4; r++) {
                int dorow = doblk * 128 + wave * 32 + i * 16 + lk * 4 + r;
                float bv = bias[dorow];
                float v0 = acc[t][i][0][r] + bv;
                float v1 = acc[t][i][1][r] + bv;
                int ncol = nchunk * 128 + t * 32 + lr;
                Db[(size_t)dorow * N_ + ncol] = v0;
                Db[(size_t)dorow * N_ + ncol + 16] = v1;
                s1[i][r] += v0 + v1;
                s2[i][r] += v0 * v0 + v1 * v1;
            }
#pragma unroll
    for (int m = 1; m < 16; m <<= 1)
#pragma unroll
        for (int i = 0; i < 2; i++)
#pragma unroll
            for (int r = 0; r < 4; r++) {
                s1[i][r] += __shfl_xor(s1[i][r], m, 64);
                s2[i][r] += __shfl_xor(s2[i][r], m, 64);
            }
    if (lr == 0) {
        int pcol = b * 49 + nchunk;
#pragma unroll
        for (int i = 0; i < 2; i++)
#pragma unroll
            for (int r = 0; r < 4; r++) {
                int row = doblk * 128 + wave * 32 + i * 16 + lk * 4 + r;
                psum[(size_t)row * PSUM_COLS + pcol] = s1[i][r];
                psum[(size_t)(DO_ + row) * PSUM_COLS + pcol] = s2[i][r];
            }
    }
}

// ---------- fused attention, LDS-staged + double-buffered (unchanged) ----------
__global__ __launch_bounds__(256, 2) void attn_k(
        const unsigned short* __restrict__ thetaT,
        const unsigned short* __restrict__ phiT,
        const unsigned short* __restrict__ g,
        unsigned short* __restrict__ ttH,
        unsigned short* __restrict__ ttL) {
    __shared__ __align__(16) unsigned short phi_s[2][32][256];
    __shared__ __align__(16) unsigned short g_s[2][256][32];
    __shared__ __align__(16) unsigned short plds[4][32][32];
    const int bid = blockIdx.x;
    const int b = bid & 7;
    const int nblk = bid >> 3;
    const int wave = threadIdx.x >> 6, lane = threadIdx.x & 63;
    const int lr = lane & 15, lk = lane >> 4;
    const int n0 = nblk * 128 + wave * 32;
    const unsigned short* Q  = thetaT + ((size_t)b * N_ + n0) * DI_;
    const unsigned short* Pg = phiT + (size_t)b * M_ * DI_;
    const unsigned short* G  = g + (size_t)b * DI_ * M_;

    short8 q[2][8];
#pragma unroll
    for (int i = 0; i < 2; i++)
#pragma unroll
        for (int kd = 0; kd < 8; kd++)
            q[i][kd] = *(const short8*)(Q + (size_t)(i * 16 + lr) * DI_ + kd * 32 + lk * 8);

    float4v acc[2][16] = {};
    float rs[2][4] = {};

    auto stage = [&](int bufi, int t) {
        const unsigned short* phiRow = Pg + (size_t)t * 32 * DI_;
#pragma unroll
        for (int j = 0; j < 4; j++) {
            int chunk = wave * 4 + j;
            int row = chunk * 2 + (lane >> 5);
            int qq = ((lane & 31) * 16) ^ ((row & 7) << 4);
            const unsigned short* src = phiRow + (size_t)row * DI_ + (qq >> 1);
            unsigned short* dst = &phi_s[bufi][0][0] + chunk * 512;
            __builtin_amdgcn_global_load_lds(
                (const __attribute__((address_space(1))) unsigned int*)src,
                (__attribute__((address_space(3))) unsigned int*)dst, 16, 0, 0);
        }
#pragma unroll
        for (int j = 0; j < 4; j++) {
            int chunk = wave * 4 + j;
            int d = chunk * 16 + (lane >> 2);
            const unsigned short* src = G + (size_t)d * M_ + t * 32 + (lane & 3) * 8;
            unsigned short* dst = &g_s[bufi][0][0] + chunk * 512;
            __builtin_amdgcn_global_load_lds(
                (const __attribute__((address_space(1))) unsigned int*)src,
                (__attribute__((address_space(3))) unsigned int*)dst, 16, 0, 0);
        }
    };

    stage(0, 0);
    const int hq = (lk * 16) ^ ((lr & 7) << 4);
    int buf = 0;
    const int NT = M_ / 32;
    for (int t = 0; t < NT; t++) {
        if (t + 1 < NT) {
            stage(buf ^ 1, t + 1);
            asm volatile("s_waitcnt vmcnt(8)" ::: "memory");
        } else {
            asm volatile("s_waitcnt vmcnt(0)" ::: "memory");
        }
        __syncthreads();
        const char* phiB = (const char*)&phi_s[buf][0][0];
        float4v L[2][2] = {};
#pragma unroll
        for (int kd = 0; kd < 8; kd++) {
            short8 pb0 = *(const short8*)(phiB + lr * 512 + ((kd * 64) ^ hq));
            short8 pb1 = *(const short8*)(phiB + (16 + lr) * 512 + ((kd * 64) ^ hq));
            L[0][0] = __builtin_amdgcn_mfma_f32_16x16x32_bf16(q[0][kd], pb0, L[0][0], 0, 0, 0);
            L[0][1] = __builtin_amdgcn_mfma_f32_16x16x32_bf16(q[0][kd], pb1, L[0][1], 0, 0, 0);
            L[1][0] = __builtin_amdgcn_mfma_f32_16x16x32_bf16(q[1][kd], pb0, L[1][0], 0, 0, 0);
            L[1][1] = __builtin_amdgcn_mfma_f32_16x16x32_bf16(q[1][kd], pb1, L[1][1], 0, 0, 0);
        }
#pragma unroll
        for (int i = 0; i < 2; i++)
#pragma unroll
            for (int mj = 0; mj < 2; mj++)
#pragma unroll
                for (int r = 0; r < 4; r++) {
                    float e = exp2f(L[i][mj][r] * SCALE_LOG2E);
                    rs[i][r] += e;
                    plds[wave][i * 16 + lk * 4 + r][mj * 16 + lr] = f2bf(e);
                }
        short8 pa0 = *(const short8*)(&plds[wave][lr][lk * 8]);
        short8 pa1 = *(const short8*)(&plds[wave][16 + lr][lk * 8]);
#pragma unroll
        for (int fd = 0; fd < 16; fd++) {
            short8 gb = *(const short8*)(&g_s[buf][fd * 16 + lr][lk * 8]);
            acc[0][fd] = __builtin_amdgcn_mfma_f32_16x16x32_bf16(pa0, gb, acc[0][fd], 0, 0, 0);
            acc[1][fd] = __builtin_amdgcn_mfma_f32_16x16x32_bf16(pa1, gb, acc[1][fd], 0, 0, 0);
        }
        __syncthreads();
        buf ^= 1;
    }
#pragma unroll
    for (int s = 1; s < 16; s <<= 1)
#pragma unroll
        for (int i = 0; i < 2; i++)
#pragma unroll
            for (int r = 0; r < 4; r++) rs[i][r] += __shfl_xor(rs[i][r], s, 64);
    float inv[2][4];
#pragma unroll
    for (int i = 0; i < 2; i++)
#pragma unroll
        for (int r = 0; r < 4; r++) inv[i][r] = 1.0f / rs[i][r];
    unsigned short* OH = ttH + ((size_t)b * N_ + n0) * DI_;
    unsigned short* OL = ttL + ((size_t)b * N_ + n0) * DI_;
#pragma unroll
    for (int i = 0; i < 2; i++)
#pragma unroll
        for (int fd = 0; fd < 16; fd++)
#pragma unroll
            for (int r = 0; r < 4; r++) {
                float v = acc[i][fd][r] * inv[i][r];
                unsigned short h = f2bf(v);
                unsigned short l = f2bf(v - bf2f(h));
                size_t idx = (size_t)(i * 16 + lk * 4 + r) * DI_ + fd * 16 + lr;
                OH[idx] = h;
                OL[idx] = l;
            }
}

// ---------- BN finalize: reduce psum -> stats (mean, rsqrt(var+eps)) ----------
__global__ void bn_finalize(const float* __restrict__ psum, float* __restrict__ stats) {
    int o = blockIdx.x;  // 512
    float s = 0.f, q = 0.f;
    for (int c = threadIdx.x; c < PSUM_COLS; c += 256) {
        s += psum[(size_t)o * PSUM_COLS + c];
        q += psum[(size_t)(DO_ + o) * PSUM_COLS + c];
    }
#pragma unroll
    for (int m = 1; m < 64; m <<= 1) { s += __shfl_xor(s, m, 64); q += __shfl_xor(q, m, 64); }
    __shared__ float ws1[4], ws2[4];
    int wave = threadIdx.x >> 6;
    if ((threadIdx.x & 63) == 0) { ws1[wave] = s; ws2[wave] = q; }
    __syncthreads();
    if (threadIdx.x == 0) {
        double S = (double)ws1[0] + ws1[1] + ws1[2] + ws1[3];
        double Q = (double)ws2[0] + ws2[1] + ws2[2] + ws2[3];
        const double cnt = (double)(B_ * N_);
        double mean = S / cnt;
        double var = Q / cnt - mean * mean;
        stats[o] = (float)mean;
        stats[DO_ + o] = (float)(1.0 / sqrt(var + (double)BN_EPS));
    }
}

// ---------- BN apply + residual ----------
__global__ void bn_apply(float* __restrict__ out, const float* __restrict__ x,
                         const float* __restrict__ stats, const float* __restrict__ gamma,
                         const float* __restrict__ beta) {
    size_t i = (size_t)blockIdx.x * 256 + threadIdx.x;
    float4v v = ((const float4v*)out)[i];
    float4v xv = ((const float4v*)x)[i];
    int o = (int)((i * 4 / N_) % DO_);
    float mean = stats[o], rsig = stats[DO_ + o];
    float ga = gamma[o], be = beta[o];
    float4v r;
#pragma unroll
    for (int j = 0; j < 4; j++) r[j] = (v[j] - mean) * rsig * ga + be + xv[j];
    ((float4v*)out)[i] = r;
}

extern "C" void kernel_launch(void* const* d_in, const int* in_sizes, int n_in,
                              void* d_out, int out_size, void* d_ws, size_t ws_size,
                              hipStream_t stream) {
    const float* x       = (const float*)d_in[0];
    const float* theta_w = (const float*)d_in[1];
    const float* theta_b = (const float*)d_in[2];
    const float* phi_w   = (const float*)d_in[3];
    const float* phi_b   = (const float*)d_in[4];
    const float* g_w     = (const float*)d_in[5];
    const float* g_b     = (const float*)d_in[6];
    const float* out_w   = (const float*)d_in[7];
    const float* out_b   = (const float*)d_in[8];
    const float* bn_g    = (const float*)d_in[9];
    const float* bn_b    = (const float*)d_in[10];
    float* out = (float*)d_out;

    char* ws = (char*)d_ws;
    size_t off = 0;
    auto alloc = [&](size_t bytes) { void* p = ws + off; off += (bytes + 255) & ~(size_t)255; return p; };
    unsigned short* xT     = (unsigned short*)alloc((size_t)B_ * N_ * C_ * 2);
    unsigned short* mpT    = (unsigned short*)alloc((size_t)B_ * M_ * C_ * 2);
    unsigned short* thetaT = (unsigned short*)alloc((size_t)B_ * N_ * DI_ * 2);
    unsigned short* phiT   = (unsigned short*)alloc((size_t)B_ * M_ * DI_ * 2);
    unsigned short* gbuf   = (unsigned short*)alloc((size_t)B_ * DI_ * M_ * 2);
    unsigned short* wq     = (unsigned short*)alloc((size_t)DI_ * C_ * 2);
    unsigned short* wp     = (unsigned short*)alloc((size_t)DI_ * C_ * 2);
    unsigned short* wg     = (unsigned short*)alloc((size_t)DI_ * C_ * 2);
    unsigned short* wo     = (unsigned short*)alloc((size_t)DO_ * DI_ * 2);
    float* stats           = (float*)alloc((size_t)DO_ * 2 * 4);
    float* psum            = (float*)alloc((size_t)DO_ * 2 * PSUM_COLS * 4);
    unsigned short* ttH    = xT;
    unsigned short* ttL    = xT + (size_t)B_ * N_ * DI_;

    cast_w<<<(DI_ * C_ + 255) / 256, 256, 0, stream>>>(theta_w, wq, DI_ * C_);
    cast_w<<<(DI_ * C_ + 255) / 256, 256, 0, stream>>>(phi_w, wp, DI_ * C_);
    cast_w<<<(DI_ * C_ + 255) / 256, 256, 0, stream>>>(g_w, wg, DI_ * C_);
    cast_w<<<(DO_ * DI_ + 255) / 256, 256, 0, stream>>>(out_w, wo, DO_ * DI_);

    xpose_x<<<dim3(N_ / 64, C_ / 64, B_), 256, 0, stream>>>(x, xT);
    pool_xpose<<<dim3(C_ / 64, T_, B_), 256, 0, stream>>>(x, mpT);

    // theta: LDS-staged, XCD-chunked
    theta_gemm<<<392, 256, 0, stream>>>(xT, wq, thetaT, theta_b);
    // phi: [M,DI] = mpT[M,C] * wp[DI,C]^T
    btgemm<1><<<dim3((M_ + 63) / 64, DI_ / 64, B_), 256, 0, stream>>>(
        mpT, (size_t)M_ * C_, wp, 0, phiT, (size_t)M_ * DI_, phi_b, M_, DI_, C_);
    // g: [DI,M] = wg[DI,C] * mpT[M,C]^T
    btgemm<2><<<dim3(DI_ / 64, (M_ + 63) / 64, B_), 256, 0, stream>>>(
        wg, 0, mpT, (size_t)M_ * C_, gbuf, (size_t)DI_ * M_, g_b, DI_, M_, C_);

    // attention -> tt hi/lo (aliases xT)
    attn_k<<<dim3((N_ / 128) * 8), 256, 0, stream>>>(thetaT, phiT, gbuf, ttH, ttL);

    // out GEMM + BN partials (LDS-staged, XCD-chunked)
    out_gemm<<<1568, 256, 0, stream>>>(wo, ttH, ttL, out, out_b, psum);

    // BN
    bn_finalize<<<DO_, 256, 0, stream>>>(psum, stats);
    bn_apply<<<(size_t)B_ * DO_ * N_ / 4 / 256, 256, 0, stream>>>(out, x, stats, bn_g, bn_b);
}